// Round 8
// baseline (86.315 us; speedup 1.0000x reference)
//
#include <hip/hip_runtime.h>
#include <hip/hip_bf16.h>

#define BB 8192
#define TT 50
#define II 50
#define HH 10
#define CC 5

typedef __attribute__((ext_vector_type(8))) short short8;
typedef __attribute__((ext_vector_type(4))) float f32x4;

struct U4 { unsigned x, y, z, w; };
__device__ __forceinline__ short8 toB(unsigned a, unsigned b, unsigned c, unsigned d) {
    U4 u{a, b, c, d};
    return __builtin_bit_cast(short8, u);
}

__device__ __forceinline__ float fast_tanh(float x) {
    float e = __expf(2.0f * x);
    return 1.0f - 2.0f * __builtin_amdgcn_rcpf(e + 1.0f);
}
__device__ __forceinline__ unsigned short bfbits(float f) {
    __hip_bfloat16 h = __float2bfloat16(f);
    union { __hip_bfloat16 h; unsigned short u; } cv;
    cv.h = h;
    return cv.u;
}
__device__ __forceinline__ unsigned packbf(float a, float b) {
    return ((unsigned)bfbits(b) << 16) | (unsigned)bfbits(a);
}

__device__ __forceinline__ void uswap16(unsigned& u, unsigned& v) {
#if __has_builtin(__builtin_amdgcn_permlane16_swap)
    auto r = __builtin_amdgcn_permlane16_swap(u, v, false, false);
    u = r[0]; v = r[1];
#else
    asm("s_nop 1\n\tv_permlane16_swap_b32 %0, %1\n\ts_nop 0" : "+v"(u), "+v"(v));
#endif
}
__device__ __forceinline__ void uswap32(unsigned& u, unsigned& v) {
#if __has_builtin(__builtin_amdgcn_permlane32_swap)
    auto r = __builtin_amdgcn_permlane32_swap(u, v, false, false);
    u = r[0]; v = r[1];
#else
    asm("s_nop 1\n\tv_permlane32_swap_b32 %0, %1\n\ts_nop 0" : "+v"(u), "+v"(v));
#endif
}
__device__ __forceinline__ void fswap16(float& u, float& v) {
    unsigned a = __float_as_uint(u), b = __float_as_uint(v);
    uswap16(a, b);
    u = __uint_as_float(a); v = __uint_as_float(b);
}
__device__ __forceinline__ void fswap32(float& u, float& v) {
    unsigned a = __float_as_uint(u), b = __float_as_uint(v);
    uswap32(a, b);
    u = __uint_as_float(a); v = __uint_as_float(b);
}

// Broadcast the 5 packed row-dwords of one h-vector (rows 01,23,45,67,89) from
// their home lane-groups to ALL lanes. a = pack(rows 4g,4g+1), b = pack(4g+2,4g+3).
struct BC { unsigned a0, a1, a2, b0, b1; };  // a0=r01, b0=r23, a1=r45, b1=r67, a2=r89
__device__ __forceinline__ BC broadcast5(unsigned a, unsigned bq, bool f16lo, bool f32lo) {
    BC r;
    unsigned u, v;
    u = a; v = a; uswap16(u, v);
    unsigned alo = f16lo ? u : v, ahi = f16lo ? v : u;
    u = alo; v = alo; uswap32(u, v);
    r.a0 = f32lo ? u : v;
    r.a2 = f32lo ? v : u;
    u = ahi; v = ahi; uswap32(u, v);
    r.a1 = f32lo ? u : v;
    u = bq; v = bq; uswap16(u, v);
    unsigned blo = f16lo ? u : v, bhi = f16lo ? v : u;
    u = blo; v = blo; uswap32(u, v);
    r.b0 = f32lo ? u : v;
    u = bhi; v = bhi; uswap32(u, v);
    r.b1 = f32lo ? u : v;
    return r;
}

// K1: P[t][j][b] = sum_i x[b][t][i] * Wih0[j][i] + (bih0[j]+bhh0[j])
__global__ __launch_bounds__(256) void k_proj0(
    const float* __restrict__ x, const float* __restrict__ Wih0,
    const float* __restrict__ bih0, const float* __restrict__ bhh0,
    float* __restrict__ P) {
    int gid = blockIdx.x * 256 + threadIdx.x;
    int b = gid & (BB - 1);
    int t = gid >> 13;
    const float2* xr = (const float2*)(x + ((size_t)b * TT + t) * II);
    float2 xv[II / 2];
#pragma unroll
    for (int i = 0; i < II / 2; i++) xv[i] = xr[i];
#pragma unroll
    for (int j = 0; j < HH; j++) {
        float a = bih0[j] + bhh0[j];
        const float2* w = (const float2*)(Wih0 + j * II);
#pragma unroll
        for (int i = 0; i < II / 2; i++) {
            float2 wv = w[i];
            a = fmaf(wv.x, xv[i].x, a);
            a = fmaf(wv.y, xv[i].y, a);
        }
        P[((size_t)t * HH + j) * BB + b] = a;
    }
}

// K2: fused 3-layer recurrence + FC via MFMA, layer-pipelined (ILP=3),
// with the ENTIRE per-block P slice staged to LDS upfront: the t-loop
// touches no global memory at all.
__global__ __launch_bounds__(64, 1) void k_fused(
    const float* __restrict__ h0all,
    const float* __restrict__ Whh0,
    const float* __restrict__ Wih1, const float* __restrict__ Whh1,
    const float* __restrict__ bih1, const float* __restrict__ bhh1,
    const float* __restrict__ Wih2, const float* __restrict__ Whh2,
    const float* __restrict__ bih2, const float* __restrict__ bhh2,
    const float* __restrict__ fcw, const float* __restrict__ fcb,
    const float* __restrict__ P, float* __restrict__ out) {
    __shared__ __align__(16) float sfc[TT * CC * 16];  // fcw packed by j-row, 16 KB
    __shared__ __align__(16) float sp[TT * HH * 16];   // P slice [row=t*10+j][16 b], 32 KB

    const int lane = threadIdx.x;
    const int bl = lane & 15;
    const int g = lane >> 4;
    const int bb0 = blockIdx.x * 16;
    const int b = bb0 + bl;

    // ---- stage P slice: sp[row*16+d] = P[row*BB + bb0 + d], 500 rows ----
    {
        f32x4 tmp[16];
#pragma unroll
        for (int grp = 0; grp < 2; ++grp) {
#pragma unroll
            for (int k = 0; k < 16; ++k) {
                int i = lane + (grp * 16 + k) * 64;   // float4 index, < 2000
                if (i < TT * HH * 4) {
                    int row = i >> 2, off = (i & 3) << 2;
                    tmp[k] = *(const f32x4*)(P + (size_t)row * BB + bb0 + off);
                }
            }
#pragma unroll
            for (int k = 0; k < 16; ++k) {
                int i = lane + (grp * 16 + k) * 64;
                if (i < TT * HH * 4) {
                    int row = i >> 2, off = (i & 3) << 2;
                    *(f32x4*)&sp[(row << 4) + off] = tmp[k];
                }
            }
        }
    }

    for (int i = lane; i < TT * CC * 16; i += 64) {
        int jj = i & 15;
        int rc = i >> 4;
        int c = rc % CC;
        int t = rc / CC;
        sfc[i] = (jj < HH) ? fcw[(size_t)c * (TT * HH) + t * HH + jj] : 0.0f;
    }

    // ---- orientation probes ----
    unsigned pu, pv;
    pu = pv = (unsigned)g; uswap16(pu, pv);
    const bool f16lo = (pu == (unsigned)(g & ~1));
    pu = pv = (unsigned)g; uswap32(pu, pv);
    const bool f32lo = (pu == (unsigned)(g & ~2));

    const bool g0 = (g == 0), g1 = (g == 1), g2 = (g == 2);

    // ---- A fragments (row m = bl, k = g*8+e) — layout verified rounds 5/6/7 ----
    short8 A0, A1, A2;
    const int m = bl;
#pragma unroll
    for (int e = 0; e < 8; e++) {
        int kv = g * 8 + e;
        float v0 = 0.0f, v1 = 0.0f, v2 = 0.0f;
        if (m < HH) {
            if (kv < HH) {
                v0 = Whh0[m * HH + kv];
                v1 = Wih1[m * HH + kv];
                v2 = Wih2[m * HH + kv];
            } else if (kv >= 12 && kv < 12 + HH) {
                v1 = Whh1[m * HH + (kv - 12)];
                v2 = Whh2[m * HH + (kv - 12)];
            }
        }
        A0[e] = (short)bfbits(v0);
        A1[e] = (short)bfbits(v1);
        A2[e] = (short)bfbits(v2);
    }
    f32x4 bC1, bC2;
#pragma unroll
    for (int r = 0; r < 4; r++) {
        int j = g * 4 + r;
        bC1[r] = (j < HH) ? (bih1[j] + bhh1[j]) : 0.0f;
        bC2[r] = (j < HH) ? (bih2[j] + bhh2[j]) : 0.0f;
    }

    // ---- initial state ----
    unsigned i1a0, i1b0, i1a1, i1b1, i1a2;   // h1 init (rows 01,23,45,67,89)
    unsigned i2a0, i2b0, i2a1, i2b1, i2a2;   // h2 init
    short8 B0, B1, B2;
    {
        const float* s0 = h0all + (size_t)b * HH;
        const float* s1 = h0all + ((size_t)BB + b) * HH;
        const float* s2 = h0all + ((size_t)2 * BB + b) * HH;
        unsigned h0p[5];
#pragma unroll
        for (int r = 0; r < 5; r++) h0p[r] = packbf(s0[2 * r], s0[2 * r + 1]);
        i1a0 = packbf(s1[0], s1[1]); i1b0 = packbf(s1[2], s1[3]);
        i1a1 = packbf(s1[4], s1[5]); i1b1 = packbf(s1[6], s1[7]);
        i1a2 = packbf(s1[8], s1[9]);
        i2a0 = packbf(s2[0], s2[1]); i2b0 = packbf(s2[2], s2[3]);
        i2a1 = packbf(s2[4], s2[5]); i2b1 = packbf(s2[6], s2[7]);
        i2a2 = packbf(s2[8], s2[9]);
        B0 = toB(g0 ? h0p[0] : (g1 ? h0p[4] : 0u),
                 g0 ? h0p[1] : 0u,
                 g0 ? h0p[2] : 0u,
                 g0 ? h0p[3] : 0u);
        B1 = toB(0u, 0u, 0u, 0u);   // L1@-1: dead chain, finite
        B2 = toB(0u, 0u, 0u, 0u);   // L2@-2: dead chain, finite
    }

    float acc[CC] = {0.0f, 0.0f, 0.0f, 0.0f, 0.0f};

    f32x4 pcur;
#pragma unroll
    for (int r = 0; r < 4; r++) {
        int j = g * 4 + r;
        pcur[r] = (j < HH) ? sp[(j << 4) + bl] : 0.0f;
    }

#pragma unroll 1
    for (int i = 0; i < TT + 2; i++) {
        // FC weights for time tau = i-2 (clamped; gated below)
        int tauc = (i >= 2) ? (i - 2) : 0;
        f32x4 fcv[CC];
#pragma unroll
        for (int c = 0; c < CC; c++)
            fcv[c] = *(const f32x4*)&sfc[(tauc * CC + c) * 16 + g * 4];
        // prefetch P for time i+1 from LDS (clamped)
        int tp = (i + 1 < TT) ? (i + 1) : (TT - 1);
        f32x4 pn;
#pragma unroll
        for (int r = 0; r < 4; r++) {
            int j = g * 4 + r;
            pn[r] = (j < HH) ? sp[((tp * HH + j) << 4) + bl] : 0.0f;
        }

        // ---- three independent MFMAs (staggered timesteps) ----
        f32x4 D0 = __builtin_amdgcn_mfma_f32_16x16x32_bf16(A0, B0, pcur, 0, 0, 0);
        f32x4 D1 = __builtin_amdgcn_mfma_f32_16x16x32_bf16(A1, B1, bC1, 0, 0, 0);
        f32x4 D2 = __builtin_amdgcn_mfma_f32_16x16x32_bf16(A2, B2, bC2, 0, 0, 0);

        float th0[4], th1[4], th2[4];
#pragma unroll
        for (int r = 0; r < 4; r++) th0[r] = fast_tanh(D0[r]);
#pragma unroll
        for (int r = 0; r < 4; r++) th1[r] = fast_tanh(D1[r]);
#pragma unroll
        for (int r = 0; r < 4; r++) th2[r] = fast_tanh(D2[r]);

        BC bc0 = broadcast5(packbf(th0[0], th0[1]), packbf(th0[2], th0[3]), f16lo, f32lo);
        BC bc1 = broadcast5(packbf(th1[0], th1[1]), packbf(th1[2], th1[3]), f16lo, f32lo);
        BC bc2 = broadcast5(packbf(th2[0], th2[1]), packbf(th2[2], th2[3]), f16lo, f32lo);

        // ---- FC accumulate for time i-2 (live only when i>=2) ----
        if (i >= 2) {
#pragma unroll
            for (int c = 0; c < CC; c++) {
#pragma unroll
                for (int r = 0; r < 4; r++)
                    acc[c] = fmaf(fcv[c][r], fmaxf(th2[r], 0.0f), acc[c]);
            }
        }

        // ---- init-state overrides for pipeline fill ----
        unsigned s1a0 = (i == 0) ? i1a0 : bc1.a0;
        unsigned s1b0 = (i == 0) ? i1b0 : bc1.b0;
        unsigned s1a1 = (i == 0) ? i1a1 : bc1.a1;
        unsigned s1b1 = (i == 0) ? i1b1 : bc1.b1;
        unsigned s1a2 = (i == 0) ? i1a2 : bc1.a2;
        unsigned s2a0 = (i <= 1) ? i2a0 : bc2.a0;
        unsigned s2b0 = (i <= 1) ? i2b0 : bc2.b0;
        unsigned s2a1 = (i <= 1) ? i2a1 : bc2.a1;
        unsigned s2b1 = (i <= 1) ? i2b1 : bc2.b1;
        unsigned s2a2 = (i <= 1) ? i2a2 : bc2.a2;

        // ---- assemble next-iteration operands ----
        // B0: L0@i+1 needs h0(i)=bc0 at k0-9
        B0 = toB(g0 ? bc0.a0 : (g1 ? bc0.a2 : 0u),
                 g0 ? bc0.b0 : 0u,
                 g0 ? bc0.a1 : 0u,
                 g0 ? bc0.b1 : 0u);
        // B1: L1@i needs h0(i)=bc0 at k0-9, h1(i-1)=s1 at k12-21
        B1 = toB(g0 ? bc0.a0 : (g1 ? bc0.a2 : (g2 ? s1a1 : 0u)),
                 g0 ? bc0.b0 : (g2 ? s1b1 : 0u),
                 g0 ? bc0.a1 : (g1 ? s1a0 : (g2 ? s1a2 : 0u)),
                 g0 ? bc0.b1 : (g1 ? s1b0 : 0u));
        // B2: L2@i-1 needs h1(i-1)=s1 at k0-9, h2(i-2)=s2 at k12-21
        B2 = toB(g0 ? s1a0 : (g1 ? s1a2 : (g2 ? s2a1 : 0u)),
                 g0 ? s1b0 : (g2 ? s2b1 : 0u),
                 g0 ? s1a1 : (g1 ? s2a0 : (g2 ? s2a2 : 0u)),
                 g0 ? s1b1 : (g1 ? s2b0 : 0u));

        pcur = pn;
    }

    // reduce acc across the 4 lane groups (commutative sums, orientation-immune)
#pragma unroll
    for (int c = 0; c < CC; c++) {
        float u = acc[c], v = acc[c];
        fswap16(u, v);
        float s = u + v;
        float u2 = s, v2 = s;
        fswap32(u2, v2);
        acc[c] = u2 + v2 + fcb[c];
    }
    if (g == 0) {
#pragma unroll
        for (int c = 0; c < CC; c++) out[(size_t)b * CC + c] = acc[c];
    }
}

extern "C" void kernel_launch(void* const* d_in, const int* in_sizes, int n_in,
                              void* d_out, int out_size, void* d_ws, size_t ws_size,
                              hipStream_t stream) {
    const float* x    = (const float*)d_in[0];
    const float* h0   = (const float*)d_in[1];
    const float* Wih0 = (const float*)d_in[2];
    const float* Whh0 = (const float*)d_in[3];
    const float* bih0 = (const float*)d_in[4];
    const float* bhh0 = (const float*)d_in[5];
    const float* Wih1 = (const float*)d_in[6];
    const float* Whh1 = (const float*)d_in[7];
    const float* bih1 = (const float*)d_in[8];
    const float* bhh1 = (const float*)d_in[9];
    const float* Wih2 = (const float*)d_in[10];
    const float* Whh2 = (const float*)d_in[11];
    const float* bih2 = (const float*)d_in[12];
    const float* bhh2 = (const float*)d_in[13];
    const float* fcw  = (const float*)d_in[14];
    const float* fcb  = (const float*)d_in[15];
    float* out = (float*)d_out;
    float* P   = (float*)d_ws;   // [T][H][B] = 16.38 MB

    k_proj0<<<(BB * TT) / 256, 256, 0, stream>>>(x, Wih0, bih0, bhh0, P);
    k_fused<<<BB / 16, 64, 0, stream>>>(h0, Whh0, Wih1, Whh1, bih1, bhh1,
                                        Wih2, Whh2, bih2, bhh2, fcw, fcb, P, out);
}

// Round 9
// 61.550 us; speedup vs baseline: 1.4024x; 1.4024x over previous
//
#include <hip/hip_runtime.h>

#define BB 8192
#define TT 50
#define II 50
#define HH 10
#define CC 5

__device__ __forceinline__ float fast_tanh(float x) {
    float e = __expf(2.0f * x);
    return 1.0f - 2.0f * __builtin_amdgcn_rcpf(e + 1.0f);
}

// K1: P[t][j][b] = sum_i x[b][t][i] * Wih0[j][i] + (bih0[j]+bhh0[j])
__global__ __launch_bounds__(256) void k_proj0(
    const float* __restrict__ x, const float* __restrict__ Wih0,
    const float* __restrict__ bih0, const float* __restrict__ bhh0,
    float* __restrict__ P) {
    int gid = blockIdx.x * 256 + threadIdx.x;
    int b = gid & (BB - 1);
    int t = gid >> 13;
    const float2* xr = (const float2*)(x + ((size_t)b * TT + t) * II);
    float2 xv[II / 2];
#pragma unroll
    for (int i = 0; i < II / 2; i++) xv[i] = xr[i];
#pragma unroll
    for (int j = 0; j < HH; j++) {
        float a = bih0[j] + bhh0[j];
        const float2* w = (const float2*)(Wih0 + j * II);
#pragma unroll
        for (int i = 0; i < II / 2; i++) {
            float2 wv = w[i];
            a = fmaf(wv.x, xv[i].x, a);
            a = fmaf(wv.y, xv[i].y, a);
        }
        P[((size_t)t * HH + j) * BB + b] = a;
    }
}

// K2: fused 3-layer recurrence + FC, pure f32.
// 16 lanes per batch (lane j<10 owns row j of every weight matrix),
// 4 batches per wave -> 2048 waves = 8 waves/CU = 2/SIMD.
// h exchanged via parity-double-buffered LDS (single wave/block: in-order DS,
// no barriers). Layers staggered ILP3: iter i runs L0@t=i, L1@t=i-1, L2@t=i-2;
// all reads consume the PREVIOUS iteration's writes (full-iteration slack).
__global__ __launch_bounds__(64, 2) void k_fused(
    const float* __restrict__ h0all,
    const float* __restrict__ Whh0,
    const float* __restrict__ Wih1, const float* __restrict__ Whh1,
    const float* __restrict__ bih1, const float* __restrict__ bhh1,
    const float* __restrict__ Wih2, const float* __restrict__ Whh2,
    const float* __restrict__ bih2, const float* __restrict__ bhh2,
    const float* __restrict__ fcw, const float* __restrict__ fcb,
    const float* __restrict__ P, float* __restrict__ out) {
    __shared__ float sfcT[TT * HH * CC];              // [t][j][c], 10 KB
    __shared__ __align__(16) float sh[2][3][4][12];   // [parity][layer][grp][j]

    const int lane = threadIdx.x;
    const int j = lane & 15;
    const int grp = lane >> 4;
    const int b = blockIdx.x * 4 + grp;
    const bool jv = (j < HH);

    // stage transposed FC weights: sfcT[(t*HH+j)*CC + c] = fcw[c][t*HH+j]
    for (int idx = lane; idx < TT * HH * CC; idx += 64) {
        int r = idx / CC, c = idx - r * CC;
        sfcT[idx] = fcw[(size_t)c * (TT * HH) + r];
    }

    // per-lane weight rows (row j of each matrix); zeros for j >= 10
    float w0[HH], wi1[HH], wh1[HH], wi2[HH], wh2[HH];
    float bs1 = 0.0f, bs2 = 0.0f, h1i = 0.0f, h2i = 0.0f;
    if (jv) {
#pragma unroll
        for (int k = 0; k < HH; k++) {
            w0[k]  = Whh0[j * HH + k];
            wi1[k] = Wih1[j * HH + k];
            wh1[k] = Whh1[j * HH + k];
            wi2[k] = Wih2[j * HH + k];
            wh2[k] = Whh2[j * HH + k];
        }
        bs1 = bih1[j] + bhh1[j];
        bs2 = bih2[j] + bhh2[j];
        h1i = h0all[(size_t)BB * HH + (size_t)b * HH + j];
        h2i = h0all[(size_t)2 * BB * HH + (size_t)b * HH + j];
    } else {
#pragma unroll
        for (int k = 0; k < HH; k++) {
            w0[k] = wi1[k] = wh1[k] = wi2[k] = wh2[k] = 0.0f;
        }
    }

    // prologue: write initial states into read-parity of iteration 0 (pr=1)
    if (j < 12) {
        float h0i = jv ? h0all[(size_t)b * HH + j] : 0.0f;
        sh[1][0][grp][j] = h0i;                 // h0(-1)
        sh[1][1][grp][j] = h1i;                 // h1(-2) placeholder (dead input)
        sh[1][2][grp][j] = h2i;                 // h2(-3) placeholder (dead input)
    }

    float acc[CC] = {0.0f, 0.0f, 0.0f, 0.0f, 0.0f};
    float pcur = jv ? P[(size_t)j * BB + b] : 0.0f;   // P[0][j][b]

#pragma unroll 1
    for (int i = 0; i < TT + 2; i++) {
        const int pr = (i + 1) & 1;   // read parity  = (i-1)&1
        const int pw = i & 1;         // write parity

        // ---- h-vector reads (broadcast within grp; prev iteration's writes) ----
        float hv0[HH], hv1[HH], hv2[HH];
        {
            const float* b0 = &sh[pr][0][grp][0];
            const float* b1 = &sh[pr][1][grp][0];
            const float* b2 = &sh[pr][2][grp][0];
            float4 a4 = *(const float4*)(b0);
            float4 b4 = *(const float4*)(b0 + 4);
            float2 c2 = *(const float2*)(b0 + 8);
            hv0[0] = a4.x; hv0[1] = a4.y; hv0[2] = a4.z; hv0[3] = a4.w;
            hv0[4] = b4.x; hv0[5] = b4.y; hv0[6] = b4.z; hv0[7] = b4.w;
            hv0[8] = c2.x; hv0[9] = c2.y;
            a4 = *(const float4*)(b1); b4 = *(const float4*)(b1 + 4); c2 = *(const float2*)(b1 + 8);
            hv1[0] = a4.x; hv1[1] = a4.y; hv1[2] = a4.z; hv1[3] = a4.w;
            hv1[4] = b4.x; hv1[5] = b4.y; hv1[6] = b4.z; hv1[7] = b4.w;
            hv1[8] = c2.x; hv1[9] = c2.y;
            a4 = *(const float4*)(b2); b4 = *(const float4*)(b2 + 4); c2 = *(const float2*)(b2 + 8);
            hv2[0] = a4.x; hv2[1] = a4.y; hv2[2] = a4.z; hv2[3] = a4.w;
            hv2[4] = b4.x; hv2[5] = b4.y; hv2[6] = b4.z; hv2[7] = b4.w;
            hv2[8] = c2.x; hv2[9] = c2.y;
        }

        // ---- prefetch next P (clamped; dead beyond t=49) ----
        int tp = (i + 1 < TT) ? (i + 1) : (TT - 1);
        float pn = jv ? P[(size_t)(tp * HH + j) * BB + b] : 0.0f;

        // ---- three staggered layer rows ----
        float a0 = pcur, a1 = bs1, a2 = bs2;
#pragma unroll
        for (int k = 0; k < HH; k++) {
            a0 = fmaf(w0[k],  hv0[k], a0);
            a1 = fmaf(wi1[k], hv0[k], a1);
            a1 = fmaf(wh1[k], hv1[k], a1);
            a2 = fmaf(wi2[k], hv1[k], a2);
            a2 = fmaf(wh2[k], hv2[k], a2);
        }
        float h0o = fast_tanh(a0);
        float h1o = fast_tanh(a1);
        float h2o = fast_tanh(a2);

        // ---- FC accumulate for t = i-2 (live when i>=2) ----
        if (i >= 2 && jv) {
            float rl = fmaxf(h2o, 0.0f);
            int base = ((i - 2) * HH + j) * CC;
#pragma unroll
            for (int c = 0; c < CC; c++) acc[c] = fmaf(sfcT[base + c], rl, acc[c]);
        }

        // ---- writes (init overrides during pipeline fill) ----
        if (j < 12) {
            float v1 = (i == 0) ? h1i : h1o;   // h1(-1) at i=0
            float v2 = (i <= 1) ? h2i : h2o;   // h2(-1)/h2(-2) at i<=1
            sh[pw][0][grp][j] = h0o;           // j=10,11 naturally 0
            sh[pw][1][grp][j] = v1;
            sh[pw][2][grp][j] = v2;
        }
        pcur = pn;
    }

    // reduce acc across the 16-lane group (lanes j>=10 hold zeros)
#pragma unroll
    for (int c = 0; c < CC; c++) {
        float a = acc[c];
        a += __shfl_xor(a, 1);
        a += __shfl_xor(a, 2);
        a += __shfl_xor(a, 4);
        a += __shfl_xor(a, 8);
        acc[c] = a + fcb[c];
    }
    if (j == 0) {
#pragma unroll
        for (int c = 0; c < CC; c++) out[(size_t)b * CC + c] = acc[c];
    }
}

extern "C" void kernel_launch(void* const* d_in, const int* in_sizes, int n_in,
                              void* d_out, int out_size, void* d_ws, size_t ws_size,
                              hipStream_t stream) {
    const float* x    = (const float*)d_in[0];
    const float* h0   = (const float*)d_in[1];
    const float* Wih0 = (const float*)d_in[2];
    const float* Whh0 = (const float*)d_in[3];
    const float* bih0 = (const float*)d_in[4];
    const float* bhh0 = (const float*)d_in[5];
    const float* Wih1 = (const float*)d_in[6];
    const float* Whh1 = (const float*)d_in[7];
    const float* bih1 = (const float*)d_in[8];
    const float* bhh1 = (const float*)d_in[9];
    const float* Wih2 = (const float*)d_in[10];
    const float* Whh2 = (const float*)d_in[11];
    const float* bih2 = (const float*)d_in[12];
    const float* bhh2 = (const float*)d_in[13];
    const float* fcw  = (const float*)d_in[14];
    const float* fcb  = (const float*)d_in[15];
    float* out = (float*)d_out;
    float* P   = (float*)d_ws;   // [T][H][B] = 16.38 MB

    k_proj0<<<(BB * TT) / 256, 256, 0, stream>>>(x, Wih0, bih0, bhh0, P);
    k_fused<<<BB / 4, 64, 0, stream>>>(h0, Whh0, Wih1, Whh1, bih1, bhh1,
                                       Wih2, Whh2, bih2, bhh2, fcw, fcb, P, out);
}

// Round 10
// 55.544 us; speedup vs baseline: 1.5540x; 1.1081x over previous
//
#include <hip/hip_runtime.h>

#define BB 8192
#define TT 50
#define II 50
#define HH 10
#define CC 5

__device__ __forceinline__ float fast_tanh(float x) {
    float e = __expf(2.0f * x);
    return 1.0f - 2.0f * __builtin_amdgcn_rcpf(e + 1.0f);
}

// K1: P[t][j][b] = sum_i x[b][t][i] * Wih0[j][i] + (bih0[j]+bhh0[j])
__global__ __launch_bounds__(256) void k_proj0(
    const float* __restrict__ x, const float* __restrict__ Wih0,
    const float* __restrict__ bih0, const float* __restrict__ bhh0,
    float* __restrict__ P) {
    int gid = blockIdx.x * 256 + threadIdx.x;
    int b = gid & (BB - 1);
    int t = gid >> 13;
    const float2* xr = (const float2*)(x + ((size_t)b * TT + t) * II);
    float2 xv[II / 2];
#pragma unroll
    for (int i = 0; i < II / 2; i++) xv[i] = xr[i];
#pragma unroll
    for (int j = 0; j < HH; j++) {
        float a = bih0[j] + bhh0[j];
        const float2* w = (const float2*)(Wih0 + j * II);
#pragma unroll
        for (int i = 0; i < II / 2; i++) {
            float2 wv = w[i];
            a = fmaf(wv.x, xv[i].x, a);
            a = fmaf(wv.y, xv[i].y, a);
        }
        P[((size_t)t * HH + j) * BB + b] = a;
    }
}

// K2: fused 3-layer recurrence + FC, pure f32.
// 16 lanes per batch (lane j<10 owns row j of every weight matrix).
// 256-thread blocks = 4 waves sharing one sfcT copy -> 4 blocks/CU = 16 waves/CU.
// Waves independent after the single __syncthreads (disjoint sh regions,
// in-order DS within each wave; parity double-buffer, no further barriers).
// Layers staggered ILP3: iter i runs L0@t=i, L1@t=i-1, L2@t=i-2.
// P prefetch rotated 2-deep to cover L2/L3 latency on the scattered reads.
__global__ __launch_bounds__(256, 4) void k_fused(
    const float* __restrict__ h0all,
    const float* __restrict__ Whh0,
    const float* __restrict__ Wih1, const float* __restrict__ Whh1,
    const float* __restrict__ bih1, const float* __restrict__ bhh1,
    const float* __restrict__ Wih2, const float* __restrict__ Whh2,
    const float* __restrict__ bih2, const float* __restrict__ bhh2,
    const float* __restrict__ fcw, const float* __restrict__ fcb,
    const float* __restrict__ P, float* __restrict__ out) {
    __shared__ float sfcT[TT * HH * CC];               // [t][j][c], 10 KB (shared by 4 waves)
    __shared__ __align__(16) float sh[2][3][16][12];   // [parity][layer][g16][j], 4.6 KB

    const int tid = threadIdx.x;
    const int j = tid & 15;
    const int g16 = tid >> 4;             // 0..15: wave = g16>>2, grp-in-wave = g16&3
    const int b = blockIdx.x * 16 + g16;
    const bool jv = (j < HH);

    // stage transposed FC weights: sfcT[(t*HH+j)*CC + c] = fcw[c][t*HH+j]
    for (int idx = tid; idx < TT * HH * CC; idx += 256) {
        int r = idx / CC, c = idx - r * CC;
        sfcT[idx] = fcw[(size_t)c * (TT * HH) + r];
    }

    // per-lane weight rows (row j of each matrix); zeros for j >= 10
    float w0[HH], wi1[HH], wh1[HH], wi2[HH], wh2[HH];
    float bs1 = 0.0f, bs2 = 0.0f, h1i = 0.0f, h2i = 0.0f;
    if (jv) {
#pragma unroll
        for (int k = 0; k < HH; k++) {
            w0[k]  = Whh0[j * HH + k];
            wi1[k] = Wih1[j * HH + k];
            wh1[k] = Whh1[j * HH + k];
            wi2[k] = Wih2[j * HH + k];
            wh2[k] = Whh2[j * HH + k];
        }
        bs1 = bih1[j] + bhh1[j];
        bs2 = bih2[j] + bhh2[j];
        h1i = h0all[(size_t)BB * HH + (size_t)b * HH + j];
        h2i = h0all[(size_t)2 * BB * HH + (size_t)b * HH + j];
    } else {
#pragma unroll
        for (int k = 0; k < HH; k++) {
            w0[k] = wi1[k] = wh1[k] = wi2[k] = wh2[k] = 0.0f;
        }
    }

    // prologue: write initial states into read-parity of iteration 0 (pr=1)
    if (j < 12) {
        float h0i = jv ? h0all[(size_t)b * HH + j] : 0.0f;
        sh[1][0][g16][j] = h0i;                 // h0(-1)
        sh[1][1][g16][j] = (j < HH) ? h1i : 0.0f;
        sh[1][2][g16][j] = (j < HH) ? h2i : 0.0f;
    }

    __syncthreads();   // sfcT ready; waves independent from here on

    float acc[CC] = {0.0f, 0.0f, 0.0f, 0.0f, 0.0f};
    // 2-deep P rotation: pc = P[t=i], p1 = P[t=i+1], p2 loaded for t=i+2
    float pc = jv ? P[(size_t)j * BB + b] : 0.0f;
    float p1 = jv ? P[(size_t)(((1 < TT) ? 1 : TT - 1) * HH + j) * BB + b] : 0.0f;

#pragma unroll 1
    for (int i = 0; i < TT + 2; i++) {
        const int pr = (i + 1) & 1;   // read parity  = (i-1)&1
        const int pw = i & 1;         // write parity

        // ---- prefetch P for t = i+2 (clamped; dead beyond t=49) ----
        int tp = (i + 2 < TT) ? (i + 2) : (TT - 1);
        float p2 = jv ? P[(size_t)(tp * HH + j) * BB + b] : 0.0f;

        // ---- h-vector reads (broadcast within grp; prev iteration's writes) ----
        float hv0[HH], hv1[HH], hv2[HH];
        {
            const float* b0 = &sh[pr][0][g16][0];
            const float* b1 = &sh[pr][1][g16][0];
            const float* b2 = &sh[pr][2][g16][0];
            float4 a4 = *(const float4*)(b0);
            float4 b4 = *(const float4*)(b0 + 4);
            float2 c2 = *(const float2*)(b0 + 8);
            hv0[0] = a4.x; hv0[1] = a4.y; hv0[2] = a4.z; hv0[3] = a4.w;
            hv0[4] = b4.x; hv0[5] = b4.y; hv0[6] = b4.z; hv0[7] = b4.w;
            hv0[8] = c2.x; hv0[9] = c2.y;
            a4 = *(const float4*)(b1); b4 = *(const float4*)(b1 + 4); c2 = *(const float2*)(b1 + 8);
            hv1[0] = a4.x; hv1[1] = a4.y; hv1[2] = a4.z; hv1[3] = a4.w;
            hv1[4] = b4.x; hv1[5] = b4.y; hv1[6] = b4.z; hv1[7] = b4.w;
            hv1[8] = c2.x; hv1[9] = c2.y;
            a4 = *(const float4*)(b2); b4 = *(const float4*)(b2 + 4); c2 = *(const float2*)(b2 + 8);
            hv2[0] = a4.x; hv2[1] = a4.y; hv2[2] = a4.z; hv2[3] = a4.w;
            hv2[4] = b4.x; hv2[5] = b4.y; hv2[6] = b4.z; hv2[7] = b4.w;
            hv2[8] = c2.x; hv2[9] = c2.y;
        }

        // ---- three staggered layer rows ----
        float a0 = pc, a1 = bs1, a2 = bs2;
#pragma unroll
        for (int k = 0; k < HH; k++) {
            a0 = fmaf(w0[k],  hv0[k], a0);
            a1 = fmaf(wi1[k], hv0[k], a1);
            a1 = fmaf(wh1[k], hv1[k], a1);
            a2 = fmaf(wi2[k], hv1[k], a2);
            a2 = fmaf(wh2[k], hv2[k], a2);
        }
        float h0o = fast_tanh(a0);
        float h1o = fast_tanh(a1);
        float h2o = fast_tanh(a2);

        // ---- FC accumulate for t = i-2 (live when i>=2) ----
        if (i >= 2 && jv) {
            float rl = fmaxf(h2o, 0.0f);
            int base = ((i - 2) * HH + j) * CC;
#pragma unroll
            for (int c = 0; c < CC; c++) acc[c] = fmaf(sfcT[base + c], rl, acc[c]);
        }

        // ---- writes (init overrides during pipeline fill) ----
        if (j < 12) {
            float v1 = (i == 0) ? h1i : h1o;   // h1(-1) at i=0
            float v2 = (i <= 1) ? h2i : h2o;   // h2(-1)/h2(-2) at i<=1
            sh[pw][0][g16][j] = h0o;           // j=10,11 naturally 0
            sh[pw][1][g16][j] = v1;
            sh[pw][2][g16][j] = v2;
        }
        pc = p1;
        p1 = p2;
    }

    // reduce acc across the 16-lane group (lanes j>=10 hold zeros)
#pragma unroll
    for (int c = 0; c < CC; c++) {
        float a = acc[c];
        a += __shfl_xor(a, 1);
        a += __shfl_xor(a, 2);
        a += __shfl_xor(a, 4);
        a += __shfl_xor(a, 8);
        acc[c] = a + fcb[c];
    }
    if (j == 0) {
#pragma unroll
        for (int c = 0; c < CC; c++) out[(size_t)b * CC + c] = acc[c];
    }
}

extern "C" void kernel_launch(void* const* d_in, const int* in_sizes, int n_in,
                              void* d_out, int out_size, void* d_ws, size_t ws_size,
                              hipStream_t stream) {
    const float* x    = (const float*)d_in[0];
    const float* h0   = (const float*)d_in[1];
    const float* Wih0 = (const float*)d_in[2];
    const float* Whh0 = (const float*)d_in[3];
    const float* bih0 = (const float*)d_in[4];
    const float* bhh0 = (const float*)d_in[5];
    const float* Wih1 = (const float*)d_in[6];
    const float* Whh1 = (const float*)d_in[7];
    const float* bih1 = (const float*)d_in[8];
    const float* bhh1 = (const float*)d_in[9];
    const float* Wih2 = (const float*)d_in[10];
    const float* Whh2 = (const float*)d_in[11];
    const float* bih2 = (const float*)d_in[12];
    const float* bhh2 = (const float*)d_in[13];
    const float* fcw  = (const float*)d_in[14];
    const float* fcb  = (const float*)d_in[15];
    float* out = (float*)d_out;
    float* P   = (float*)d_ws;   // [T][H][B] = 16.38 MB

    k_proj0<<<(BB * TT) / 256, 256, 0, stream>>>(x, Wih0, bih0, bhh0, P);
    k_fused<<<BB / 16, 256, 0, stream>>>(h0, Whh0, Wih1, Whh1, bih1, bhh1,
                                         Wih2, Whh2, bih2, bhh2, fcw, fcb, P, out);
}